// Round 14
// baseline (256.371 us; speedup 1.0000x reference)
//
#include <hip/hip_runtime.h>
#include <hip/hip_bf16.h>
#include <math.h>

typedef float f32x4 __attribute__((ext_vector_type(4)));
typedef __bf16 bf16x8 __attribute__((ext_vector_type(8)));
typedef __hip_bfloat16 bf16;

constexpr int T_SEQ = 2048;
constexpr int C_EMB = 1024;
constexpr int N_HEAD = 16;
constexpr int D_HEAD = 64;
constexpr int BATCH = 2;
constexpr int M_ROWS = BATCH * T_SEQ;   // 4096
constexpr int HIDDEN_DIM = 4096;

static __device__ __forceinline__ f32x4 zero4() {
  f32x4 z; z[0] = 0.f; z[1] = 0.f; z[2] = 0.f; z[3] = 0.f; return z;
}

static __device__ __forceinline__ void gl_lds16(const bf16* g, bf16* l) {
  __builtin_amdgcn_global_load_lds(
      (const __attribute__((address_space(1))) unsigned int*)g,
      (__attribute__((address_space(3))) unsigned int*)l, 16, 0, 0);
}

#define BAR() asm volatile("s_barrier" ::: "memory")

// ---------------- merged preproc: weight cast+transpose (4 weights) + LN1 ----------------
__global__ __launch_bounds__(256) void preproc(
    const float* __restrict__ qkv_w, bf16* __restrict__ Wqkv,
    const float* __restrict__ out_w, bf16* __restrict__ Wout,
    const float* __restrict__ fc1_w, bf16* __restrict__ W1,
    const float* __restrict__ fc2_w, bf16* __restrict__ W2,
    const float* __restrict__ x, const float* __restrict__ gamma,
    const float* __restrict__ beta, bf16* __restrict__ xb) {
  __shared__ float smem[32 * 33];
  int id = blockIdx.x;
  int t = threadIdx.x;
  if (id >= 12288) {
    int row = id - 12288;
    const float* xr = x + (size_t)row * C_EMB;
    float4 v = *(const float4*)&xr[t * 4];
    float s = v.x + v.y + v.z + v.w;
    float ss = v.x * v.x + v.y * v.y + v.z * v.z + v.w * v.w;
#pragma unroll
    for (int off = 32; off > 0; off >>= 1) {
      s += __shfl_down(s, off, 64);
      ss += __shfl_down(ss, off, 64);
    }
    int w = t >> 6;
    if ((t & 63) == 0) { smem[w] = s; smem[4 + w] = ss; }
    __syncthreads();
    s = smem[0] + smem[1] + smem[2] + smem[3];
    ss = smem[4] + smem[5] + smem[6] + smem[7];
    float mu = s * (1.0f / C_EMB);
    float var = ss * (1.0f / C_EMB) - mu * mu;
    float rstd = rsqrtf(var + 1e-5f);
    float4 g4 = *(const float4*)&gamma[t * 4];
    float4 b4 = *(const float4*)&beta[t * 4];
    bf16* orow = xb + (size_t)row * C_EMB + t * 4;
    orow[0] = __float2bfloat16((v.x - mu) * rstd * g4.x + b4.x);
    orow[1] = __float2bfloat16((v.y - mu) * rstd * g4.y + b4.y);
    orow[2] = __float2bfloat16((v.z - mu) * rstd * g4.z + b4.z);
    orow[3] = __float2bfloat16((v.w - mu) * rstd * g4.w + b4.w);
    return;
  }
  const float* src; bf16* dst; int K, N, tt;
  if (id < 3072)      { src = qkv_w; dst = Wqkv; K = 1024; N = 3072; tt = id; }
  else if (id < 4096) { src = out_w; dst = Wout; K = 1024; N = 1024; tt = id - 3072; }
  else if (id < 8192) { src = fc1_w; dst = W1;   K = 1024; N = 4096; tt = id - 4096; }
  else                { src = fc2_w; dst = W2;   K = 4096; N = 1024; tt = id - 8192; }
  int ntx = N >> 5;
  int n0 = (tt % ntx) * 32, k0 = (tt / ntx) * 32;
  float (*tile)[33] = (float(*)[33])smem;
  int tx = t & 31, ty = t >> 5;
#pragma unroll
  for (int i = 0; i < 4; ++i)
    tile[ty + 8 * i][tx] = src[(size_t)(k0 + ty + 8 * i) * N + n0 + tx];
  __syncthreads();
#pragma unroll
  for (int i = 0; i < 4; ++i)
    dst[(size_t)(n0 + ty + 8 * i) * K + k0 + tx] = __float2bfloat16(tile[tx][ty + 8 * i]);
}

// ---------------- LayerNorm: fp32 in -> bf16 out ----------------
__global__ __launch_bounds__(256) void ln_kernel(const float* __restrict__ x,
                                                 const float* __restrict__ gamma,
                                                 const float* __restrict__ beta,
                                                 bf16* __restrict__ out) {
  int row = blockIdx.x;
  const float* xr = x + (size_t)row * C_EMB;
  int t = threadIdx.x;
  float4 v = *(const float4*)&xr[t * 4];
  float s = v.x + v.y + v.z + v.w;
  float ss = v.x * v.x + v.y * v.y + v.z * v.z + v.w * v.w;
#pragma unroll
  for (int off = 32; off > 0; off >>= 1) {
    s += __shfl_down(s, off, 64);
    ss += __shfl_down(ss, off, 64);
  }
  __shared__ float sbuf[8];
  int w = t >> 6;
  if ((t & 63) == 0) { sbuf[w] = s; sbuf[4 + w] = ss; }
  __syncthreads();
  s = sbuf[0] + sbuf[1] + sbuf[2] + sbuf[3];
  ss = sbuf[4] + sbuf[5] + sbuf[6] + sbuf[7];
  float mu = s * (1.0f / C_EMB);
  float var = ss * (1.0f / C_EMB) - mu * mu;
  float rstd = rsqrtf(var + 1e-5f);
  float4 g4 = *(const float4*)&gamma[t * 4];
  float4 b4 = *(const float4*)&beta[t * 4];
  bf16* orow = out + (size_t)row * C_EMB + t * 4;
  orow[0] = __float2bfloat16((v.x - mu) * rstd * g4.x + b4.x);
  orow[1] = __float2bfloat16((v.y - mu) * rstd * g4.y + b4.y);
  orow[2] = __float2bfloat16((v.z - mu) * rstd * g4.z + b4.z);
  orow[3] = __float2bfloat16((v.w - mu) * rstd * g4.w + b4.w);
}

// ---------------- GEMM 256x256, BK=64, 8 waves, 8-phase (r10-proven) ----------------
// EPI 0: scatter Q(,*0.125)/K -> [B,H,T,D]; V -> Vt [BH][D][T] directly.
// EPI 2: gelu -> bf16.
template <int EPI>
__global__ __launch_bounds__(512) void gemm8p(
    const bf16* __restrict__ A, const bf16* __restrict__ Bt,
    const float* __restrict__ bias, int M, int N, int K,
    bf16* __restrict__ out_b16,
    bf16* __restrict__ q_out, bf16* __restrict__ k_out, bf16* __restrict__ vt_out) {
  constexpr int NFR = 4;                  // BN=256
  __shared__ bf16 Asl[2][2][128 * 64];
  __shared__ bf16 Bsl[2][2][128 * 64];

  int gx = gridDim.x, nwg = gx * gridDim.y;
  int flat = blockIdx.y * gx + blockIdx.x;
  int swz = (flat & 7) * (nwg >> 3) + (flat >> 3);
  int bx = swz % gx, by = swz / gx;

  int m0 = by * 256, n0 = bx * 256;
  int t = threadIdx.x;
  int wv = t >> 6, lane = t & 63, g = lane >> 4, r16 = lane & 15;
  int wm = wv >> 2, wn = wv & 3;          // 2M x 4N wave grid

  f32x4 acc[8][NFR];
#pragma unroll
  for (int i = 0; i < 8; ++i)
#pragma unroll
    for (int j = 0; j < NFR; ++j) acc[i][j] = zero4();

  int lrow8 = lane >> 3;
  int srcg = (lane & 7) ^ lrow8;
  int NT = K / 64;

  auto stageA = [&](int tile, int h) {
    int par = tile & 1;
    const bf16* base = A + (size_t)(m0 + h * 128) * K + tile * 64;
#pragma unroll
    for (int j = 0; j < 2; ++j) {
      const bf16* src = base + (size_t)((wv * 2 + j) * 8 + lrow8) * K + srcg * 8;
      gl_lds16(src, &Asl[par][h][((wv * 2 + j) * 8) * 64]);
    }
  };
  auto stageB = [&](int tile, int h) {
    int par = tile & 1;
    const bf16* base = Bt + (size_t)(n0 + h * 128) * K + tile * 64;
#pragma unroll
    for (int j = 0; j < 2; ++j) {
      const bf16* src = base + (size_t)((wv * 2 + j) * 8 + lrow8) * K + srcg * 8;
      gl_lds16(src, &Bsl[par][h][((wv * 2 + j) * 8) * 64]);
    }
  };

  int xk[2];
#pragma unroll
  for (int kk = 0; kk < 2; ++kk) xk[kk] = (((kk * 4 + g) ^ (r16 & 7)) << 3);
  int bhalf = wn >> 1;
  int blrow0 = (wn & 1) * 64;

  stageA(0, 0); stageA(0, 1); stageB(0, 0); stageB(0, 1);
  if (NT > 1) {
    stageB(1, 0); stageB(1, 1);
    asm volatile("s_waitcnt vmcnt(4)" ::: "memory");
  } else {
    asm volatile("s_waitcnt vmcnt(0)" ::: "memory");
  }
  BAR();

  bf16x8 bfr[NFR][2];

  for (int u = 0; u < NT; ++u) {
    int par = u & 1;
    const bf16* Ab = &Asl[par][wm][0];
    const bf16* Bb = &Bsl[par][bhalf][0];
#pragma unroll
    for (int q = 0; q < 4; ++q) {
      if (q == 0) {
#pragma unroll
        for (int ni = 0; ni < NFR; ++ni)
#pragma unroll
          for (int kk = 0; kk < 2; ++kk)
            bfr[ni][kk] = *(const bf16x8*)&Bb[(blrow0 + ni * 16 + r16) * 64 + xk[kk]];
      }
      bf16x8 af[2][2];
#pragma unroll
      for (int d = 0; d < 2; ++d)
#pragma unroll
        for (int kk = 0; kk < 2; ++kk)
          af[d][kk] = *(const bf16x8*)&Ab[((2 * q + d) * 16 + r16) * 64 + xk[kk]];
      if (q == 0) { if (u + 1 < NT) stageA(u + 1, 0); }
      else if (q == 1) { if (u + 1 < NT) stageA(u + 1, 1); }
      else if (q == 2) { if (u + 2 < NT) stageB(u + 2, 0); }
      else { if (u + 2 < NT) stageB(u + 2, 1); }
      BAR();
      asm volatile("s_waitcnt lgkmcnt(0)" ::: "memory");
      __builtin_amdgcn_sched_barrier(0);
      __builtin_amdgcn_s_setprio(1);
#pragma unroll
      for (int d = 0; d < 2; ++d)
#pragma unroll
        for (int ni = 0; ni < NFR; ++ni) {
          acc[2 * q + d][ni] = __builtin_amdgcn_mfma_f32_16x16x32_bf16(af[d][0], bfr[ni][0], acc[2 * q + d][ni], 0, 0, 0);
          acc[2 * q + d][ni] = __builtin_amdgcn_mfma_f32_16x16x32_bf16(af[d][1], bfr[ni][1], acc[2 * q + d][ni], 0, 0, 0);
        }
      __builtin_amdgcn_s_setprio(0);
      if (q == 3) {
        if (u + 2 < NT)
          asm volatile("s_waitcnt vmcnt(4)" ::: "memory");
        else
          asm volatile("s_waitcnt vmcnt(0)" ::: "memory");
      }
      BAR();
    }
  }

#pragma unroll
  for (int mi = 0; mi < 8; ++mi) {
#pragma unroll
    for (int ni = 0; ni < NFR; ++ni) {
      int col = n0 + wn * 64 + ni * 16 + r16;
      float bv = bias[col];
#pragma unroll
      for (int reg = 0; reg < 4; ++reg) {
        int row = m0 + wm * 128 + mi * 16 + g * 4 + reg;
        float v = acc[mi][ni][reg] + bv;
        if constexpr (EPI == 0) {
          int part = col >> 10, cc = col & 1023;
          int hh = cc >> 6, dd = cc & 63;
          int bb = row >> 11, tt2 = row & 2047;
          if (part == 0) {
            size_t idx = (((size_t)bb * N_HEAD + hh) * T_SEQ + tt2) * D_HEAD + dd;
            q_out[idx] = __float2bfloat16(v * 0.125f);
          } else if (part == 1) {
            size_t idx = (((size_t)bb * N_HEAD + hh) * T_SEQ + tt2) * D_HEAD + dd;
            k_out[idx] = __float2bfloat16(v);
          } else {
            // V written transposed: [BH][D][T]
            size_t idx = (((size_t)bb * N_HEAD + hh) * D_HEAD + dd) * T_SEQ + tt2;
            vt_out[idx] = __float2bfloat16(v);
          }
        } else {
          float ge = 0.5f * v * (1.0f + erff(v * 0.70710678118f));
          out_b16[(size_t)row * N + col] = __float2bfloat16(ge);
        }
      }
    }
  }
}

// ---------------- GEMM 128x128, BK=64, 4 waves, 2-phase dbuf, 64KB LDS (2/CU) ----
// EPI 2: gelu->bf16.
template <int EPI>
__global__ __launch_bounds__(256) void gemmW128(
    const bf16* __restrict__ A, const bf16* __restrict__ Bt,
    const float* __restrict__ bias, int M, int N, int K,
    const float* __restrict__ res, float* __restrict__ out_f32,
    bf16* __restrict__ out_b16) {
  __shared__ bf16 Abuf[2][128 * 64];
  __shared__ bf16 Bbuf[2][128 * 64];

  int gx = gridDim.x, nwg = gx * gridDim.y;
  int flat = blockIdx.y * gx + blockIdx.x;
  int swz = (flat & 7) * (nwg >> 3) + (flat >> 3);
  int bx = swz % gx, by = swz / gx;

  int m0 = by * 128, n0 = bx * 128;
  int t = threadIdx.x;
  int wv = t >> 6, lane = t & 63, g = lane >> 4, r16 = lane & 15;
  int wm = wv >> 1, wn = wv & 1;          // 2M x 2N wave grid; per-wave 64x64

  f32x4 acc[4][4];
#pragma unroll
  for (int i = 0; i < 4; ++i)
#pragma unroll
    for (int j = 0; j < 4; ++j) acc[i][j] = zero4();

  int lrow8 = lane >> 3;
  int srcg = (lane & 7) ^ lrow8;
  int NT = K / 64;

  const bf16* gAp[4];
  const bf16* gBp[4];
#pragma unroll
  for (int i = 0; i < 4; ++i) {
    gAp[i] = A + (size_t)(m0 + (wv * 4 + i) * 8 + lrow8) * K + srcg * 8;
    gBp[i] = Bt + (size_t)(n0 + (wv * 4 + i) * 8 + lrow8) * K + srcg * 8;
  }

  int aoff[4], boff[4], xk[2];
#pragma unroll
  for (int mi = 0; mi < 4; ++mi) aoff[mi] = (wm * 64 + mi * 16 + r16) * 64;
#pragma unroll
  for (int ni = 0; ni < 4; ++ni) boff[ni] = (wn * 64 + ni * 16 + r16) * 64;
#pragma unroll
  for (int kk = 0; kk < 2; ++kk) xk[kk] = (((kk * 4 + g) ^ (r16 & 7)) << 3);

  auto stage = [&](int buf) {
#pragma unroll
    for (int i = 0; i < 4; ++i) {
      gl_lds16(gAp[i], &Abuf[buf][((wv * 4 + i) * 8) * 64]);
      gAp[i] += 64;
      gl_lds16(gBp[i], &Bbuf[buf][((wv * 4 + i) * 8) * 64]);
      gBp[i] += 64;
    }
  };

  auto compute = [&](int buf) {
    const bf16* Ab = &Abuf[buf][0];
    const bf16* Bb = &Bbuf[buf][0];
    bf16x8 bfr[4][2];
#pragma unroll
    for (int ni = 0; ni < 4; ++ni)
#pragma unroll
      for (int kk = 0; kk < 2; ++kk)
        bfr[ni][kk] = *(const bf16x8*)&Bb[boff[ni] + xk[kk]];
#pragma unroll
    for (int mi = 0; mi < 4; ++mi) {
      bf16x8 a0 = *(const bf16x8*)&Ab[aoff[mi] + xk[0]];
      bf16x8 a1 = *(const bf16x8*)&Ab[aoff[mi] + xk[1]];
#pragma unroll
      for (int ni = 0; ni < 4; ++ni) {
        acc[mi][ni] = __builtin_amdgcn_mfma_f32_16x16x32_bf16(a0, bfr[ni][0], acc[mi][ni], 0, 0, 0);
        acc[mi][ni] = __builtin_amdgcn_mfma_f32_16x16x32_bf16(a1, bfr[ni][1], acc[mi][ni], 0, 0, 0);
      }
    }
  };

  stage(0);
  __syncthreads();
  for (int tt2 = 0; tt2 < NT; ++tt2) {
    int cur = tt2 & 1;
    if (tt2 + 1 < NT) stage(cur ^ 1);
    compute(cur);
    __syncthreads();
  }

#pragma unroll
  for (int mi = 0; mi < 4; ++mi) {
#pragma unroll
    for (int ni = 0; ni < 4; ++ni) {
      int col = n0 + wn * 64 + ni * 16 + r16;
      float bv = bias[col];
#pragma unroll
      for (int reg = 0; reg < 4; ++reg) {
        int row = m0 + wm * 64 + mi * 16 + g * 4 + reg;
        float v = acc[mi][ni][reg] + bv;
        if constexpr (EPI == 1) {
          size_t idx = (size_t)row * N + col;
          out_f32[idx] = v + res[idx];
        } else {
          float ge = 0.5f * v * (1.0f + erff(v * 0.70710678118f));
          out_b16[(size_t)row * N + col] = __float2bfloat16(ge);
        }
      }
    }
  }
}

// ---------------- GEMM 128x64, BK=64, 4 waves, 48KB LDS (r12-proven) ----
// EPI 1: out = acc + bias + res (fp32).
__global__ __launch_bounds__(256) void gemmW(
    const bf16* __restrict__ A, const bf16* __restrict__ Bt,
    const float* __restrict__ bias, int M, int N, int K,
    const float* __restrict__ res, float* __restrict__ out_f32) {
  __shared__ bf16 Abuf[2][128 * 64];
  __shared__ bf16 Bbuf[2][64 * 64];

  int gx = gridDim.x, nwg = gx * gridDim.y;
  int flat = blockIdx.y * gx + blockIdx.x;
  int swz = (flat & 7) * (nwg >> 3) + (flat >> 3);
  int bx = swz % gx, by = swz / gx;

  int m0 = by * 128, n0 = bx * 64;
  int t = threadIdx.x;
  int wv = t >> 6, lane = t & 63, g = lane >> 4, r16 = lane & 15;
  int wm = wv >> 1, wn = wv & 1;

  f32x4 acc[4][2];
#pragma unroll
  for (int i = 0; i < 4; ++i)
#pragma unroll
    for (int j = 0; j < 2; ++j) acc[i][j] = zero4();

  int lrow8 = lane >> 3;
  int srcg = (lane & 7) ^ lrow8;
  int NT = K / 64;

  const bf16* gAp[4];
  const bf16* gBp[2];
#pragma unroll
  for (int i = 0; i < 4; ++i)
    gAp[i] = A + (size_t)(m0 + (wv * 4 + i) * 8 + lrow8) * K + srcg * 8;
#pragma unroll
  for (int i = 0; i < 2; ++i)
    gBp[i] = Bt + (size_t)(n0 + (wv * 2 + i) * 8 + lrow8) * K + srcg * 8;

  int aoff[4], boff[2], xk[2];
#pragma unroll
  for (int mi = 0; mi < 4; ++mi) aoff[mi] = (wm * 64 + mi * 16 + r16) * 64;
#pragma unroll
  for (int ni = 0; ni < 2; ++ni) boff[ni] = (wn * 32 + ni * 16 + r16) * 64;
#pragma unroll
  for (int kk = 0; kk < 2; ++kk) xk[kk] = (((kk * 4 + g) ^ (r16 & 7)) << 3);

  auto stage = [&](int buf) {
#pragma unroll
    for (int i = 0; i < 4; ++i) {
      gl_lds16(gAp[i], &Abuf[buf][((wv * 4 + i) * 8) * 64]);
      gAp[i] += 64;
    }
#pragma unroll
    for (int i = 0; i < 2; ++i) {
      gl_lds16(gBp[i], &Bbuf[buf][((wv * 2 + i) * 8) * 64]);
      gBp[i] += 64;
    }
  };

  auto compute = [&](int buf) {
    const bf16* Ab = &Abuf[buf][0];
    const bf16* Bb = &Bbuf[buf][0];
    bf16x8 bfr[2][2];
#pragma unroll
    for (int ni = 0; ni < 2; ++ni)
#pragma unroll
      for (int kk = 0; kk < 2; ++kk)
        bfr[ni][kk] = *(const bf16x8*)&Bb[boff[ni] + xk[kk]];
#pragma unroll
    for (int mi = 0; mi < 4; ++mi) {
      bf16x8 a0 = *(const bf16x8*)&Ab[aoff[mi] + xk[0]];
      bf16x8 a1 = *(const bf16x8*)&Ab[aoff[mi] + xk[1]];
#pragma unroll
      for (int ni = 0; ni < 2; ++ni) {
        acc[mi][ni] = __builtin_amdgcn_mfma_f32_16x16x32_bf16(a0, bfr[ni][0], acc[mi][ni], 0, 0, 0);
        acc[mi][ni] = __builtin_amdgcn_mfma_f32_16x16x32_bf16(a1, bfr[ni][1], acc[mi][ni], 0, 0, 0);
      }
    }
  };

  stage(0);
  __syncthreads();
  for (int tt2 = 0; tt2 < NT; ++tt2) {
    int cur = tt2 & 1;
    if (tt2 + 1 < NT) stage(cur ^ 1);
    compute(cur);
    __syncthreads();
  }

#pragma unroll
  for (int mi = 0; mi < 4; ++mi) {
#pragma unroll
    for (int ni = 0; ni < 2; ++ni) {
      int col = n0 + wn * 32 + ni * 16 + r16;
      float bv = bias[col];
#pragma unroll
      for (int reg = 0; reg < 4; ++reg) {
        int row = m0 + wm * 64 + mi * 16 + g * 4 + reg;
        size_t idx = (size_t)row * N + col;
        out_f32[idx] = acc[mi][ni][reg] + bv + res[idx];
      }
    }
  }
}

// ---------------- causal flash attention (round-6 proven version) ----------------
__global__ __launch_bounds__(256) void attn_kernel(const bf16* __restrict__ Q,
                                                   const bf16* __restrict__ Kg,
                                                   const bf16* __restrict__ Vt,
                                                   bf16* __restrict__ O) {
  constexpr int NQ = T_SEQ / 64;   // 32
  int p = blockIdx.x, bh = blockIdx.y;
  int qtA = p, qtB = NQ - 1 - p;
  int b = bh >> 4, h = bh & 15;
  __shared__ bf16 Ks[2][64 * 64];
  __shared__ bf16 Vs[2][64 * 64];
  __shared__ bf16 Ps[4][16 * 64];
  int t = threadIdx.x, w = t >> 6, lane = t & 63, g = lane >> 4, r16 = lane & 15;

  const bf16* QpA = Q + ((size_t)bh * T_SEQ + qtA * 64) * 64;
  const bf16* QpB = Q + ((size_t)bh * T_SEQ + qtB * 64) * 64;
  bf16x8 qfA[2], qfB[2];
#pragma unroll
  for (int kk = 0; kk < 2; ++kk) {
    qfA[kk] = *(const bf16x8*)&QpA[(w * 16 + r16) * 64 + kk * 32 + g * 8];
    qfB[kk] = *(const bf16x8*)&QpB[(w * 16 + r16) * 64 + kk * 32 + g * 8];
  }

  float lsA[4] = {0.f, 0.f, 0.f, 0.f}, lsB[4] = {0.f, 0.f, 0.f, 0.f};
  f32x4 oA[4], oB[4];
#pragma unroll
  for (int i = 0; i < 4; ++i) { oA[i] = zero4(); oB[i] = zero4(); }

  bf16* Psw = Ps[w];

  int sg0 = w * 128 + lane, sg1 = w * 128 + 64 + lane;
  int sr0 = sg0 >> 3, sc0 = (sg0 & 7) ^ (sr0 & 7);
  int sr1 = sg1 >> 3, sc1 = (sg1 & 7) ^ (sr1 & 7);

  auto stage = [&](int kt, int buf) {
    const bf16* Kp = Kg + ((size_t)bh * T_SEQ + kt * 64) * 64;
    const bf16* Vp = Vt + (size_t)bh * 64 * T_SEQ + kt * 64;
    gl_lds16(Kp + sr0 * 64 + sc0 * 8, &Ks[buf][(w * 128) * 8]);
    gl_lds16(Vp + (size_t)sr0 * T_SEQ + sc0 * 8, &Vs[buf][(w * 128) * 8]);
    gl_lds16(Kp + sr1 * 64 + sc1 * 8, &Ks[buf][(w * 128 + 64) * 8]);
    gl_lds16(Vp + (size_t)sr1 * T_SEQ + sc1 * 8, &Vs[buf][(w * 128 + 64) * 8]);
  };

  auto process = [&](const bf16x8* qf, float* ls, f32x4* o_acc, bool diag,
                     const bf16* Ksb, const bf16* Vsb) {
    f32x4 s[4];
#pragma unroll
    for (int ni = 0; ni < 4; ++ni) {
      s[ni] = zero4();
#pragma unroll
      for (int kk = 0; kk < 2; ++kk) {
        bf16x8 kf = *(const bf16x8*)&Ksb[(ni * 16 + r16) * 64 + (((kk * 4 + g) ^ (r16 & 7)) << 3)];
        s[ni] = __builtin_amdgcn_mfma_f32_16x16x32_bf16(qf[kk], kf, s[ni], 0, 0, 0);
      }
    }
    if (diag) {
#pragma unroll
      for (int ni = 0; ni < 4; ++ni) {
        int kl = ni * 16 + r16;
#pragma unroll
        for (int reg = 0; reg < 4; ++reg) {
          int ql = w * 16 + g * 4 + reg;
          if (kl > ql) s[ni][reg] = -1e30f;
        }
      }
    }
#pragma unroll
    for (int ni = 0; ni < 4; ++ni) {
#pragma unroll
      for (int reg = 0; reg < 4; ++reg) {
        float pv = __expf(s[ni][reg]);
        s[ni][reg] = pv;
        ls[reg] += pv;
        int rr = g * 4 + reg;
        Psw[rr * 64 + (((ni * 2 + (r16 >> 3)) ^ (rr & 7)) << 3) + (r16 & 7)] =
            __float2bfloat16(pv);
      }
    }
    bf16x8 pf[2];
#pragma unroll
    for (int kk = 0; kk < 2; ++kk)
      pf[kk] = *(const bf16x8*)&Psw[r16 * 64 + (((kk * 4 + g) ^ (r16 & 7)) << 3)];
#pragma unroll
    for (int nd = 0; nd < 4; ++nd)
#pragma unroll
      for (int kk = 0; kk < 2; ++kk) {
        bf16x8 vf = *(const bf16x8*)&Vsb[(nd * 16 + r16) * 64 + (((kk * 4 + g) ^ (r16 & 7)) << 3)];
        o_acc[nd] = __builtin_amdgcn_mfma_f32_16x16x32_bf16(pf[kk], vf, o_acc[nd], 0, 0, 0);
      }
  };

  stage(0, 0);
  __syncthreads();
  for (int kt = 0; kt <= qtB; ++kt) {
    int cur = kt & 1;
    if (kt + 1 <= qtB) stage(kt + 1, cur ^ 1);
    process(qfB, lsB, oB, kt == qtB, &Ks[cur][0], &Vs[cur][0]);
    if (kt <= qtA) process(qfA, lsA, oA, kt == qtA, &Ks[cur][0], &Vs[cur][0]);
    __syncthreads();
  }

#pragma unroll
  for (int reg = 0; reg < 4; ++reg) {
#pragma unroll
    for (int off = 1; off < 16; off <<= 1) {
      lsA[reg] += __shfl_xor(lsA[reg], off, 64);
      lsB[reg] += __shfl_xor(lsB[reg], off, 64);
    }
  }
#pragma unroll
  for (int reg = 0; reg < 4; ++reg) {
    float invA = 1.0f / lsA[reg];
    float invB = 1.0f / lsB[reg];
    int rowA = b * T_SEQ + qtA * 64 + w * 16 + g * 4 + reg;
    int rowB = b * T_SEQ + qtB * 64 + w * 16 + g * 4 + reg;
#pragma unroll
    for (int nd = 0; nd < 4; ++nd) {
      int col = h * 64 + nd * 16 + r16;
      O[(size_t)rowA * C_EMB + col] = __float2bfloat16(oA[nd][reg] * invA);
      O[(size_t)rowB * C_EMB + col] = __float2bfloat16(oB[nd][reg] * invB);
    }
  }
}

extern "C" void kernel_launch(void* const* d_in, const int* in_sizes, int n_in,
                              void* d_out, int out_size, void* d_ws, size_t ws_size,
                              hipStream_t stream) {
  (void)in_sizes; (void)n_in; (void)out_size; (void)ws_size;
  const float* x     = (const float*)d_in[0];
  const float* ln1_g = (const float*)d_in[1];
  const float* ln1_b = (const float*)d_in[2];
  const float* qkv_w = (const float*)d_in[3];
  const float* qkv_b = (const float*)d_in[4];
  const float* out_w = (const float*)d_in[5];
  const float* out_b = (const float*)d_in[6];
  const float* ln2_g = (const float*)d_in[7];
  const float* ln2_b = (const float*)d_in[8];
  const float* fc1_w = (const float*)d_in[9];
  const float* fc1_b = (const float*)d_in[10];
  const float* fc2_w = (const float*)d_in[11];
  const float* fc2_b = (const float*)d_in[12];
  float* out = (float*)d_out;

  char* ws = (char*)d_ws;
  size_t off = 0;
  auto alloc = [&](size_t bytes) {
    void* p = ws + off;
    off += (bytes + 255) & ~(size_t)255;
    return p;
  };
  bf16* Wqkv = (bf16*)alloc((size_t)3 * C_EMB * C_EMB * 2);          // 6MB
  bf16* Wout = (bf16*)alloc((size_t)C_EMB * C_EMB * 2);              // 2MB
  bf16* W1   = (bf16*)alloc((size_t)HIDDEN_DIM * C_EMB * 2);         // 8MB
  bf16* W2   = (bf16*)alloc((size_t)C_EMB * HIDDEN_DIM * 2);         // 8MB
  float* x2  = (float*)alloc((size_t)M_ROWS * C_EMB * 4);            // fp32 residual stream
  bf16* Xb   = (bf16*)alloc((size_t)M_ROWS * C_EMB * 2);             // X1 / O / X2n
  bf16* Qb   = (bf16*)alloc((size_t)M_ROWS * C_EMB * 2 * 3);         // Q,K,Vt ; later H1
  bf16* Kb   = Qb + (size_t)M_ROWS * C_EMB;
  bf16* Vtb  = Kb + (size_t)M_ROWS * C_EMB;
  bf16* H1   = (bf16*)alloc((size_t)M_ROWS * HIDDEN_DIM * 2);        // 32MB

  // merged weight cast + LN1 (1 launch)
  preproc<<<16384, 256, 0, stream>>>(qkv_w, Wqkv, out_w, Wout, fc1_w, W1, fc2_w, W2,
                                     x, ln1_g, ln1_b, Xb);

  // QKV projection (8-phase 256x256); Q pre-scaled 1/8, V written directly transposed
  gemm8p<0><<<dim3(3 * C_EMB / 256, M_ROWS / 256), 512, 0, stream>>>(
      Xb, Wqkv, qkv_b, M_ROWS, 3 * C_EMB, C_EMB,
      nullptr, Qb, Kb, Vtb);

  // attention -> O (Xb, [B,T,C])
  attn_kernel<<<dim3(T_SEQ / 128, BATCH * N_HEAD), 256, 0, stream>>>(Qb, Kb, Vtb, Xb);

  // out-proj (128x64, grid 512): x2 = attnout@Wout + bias + x
  gemmW<<<dim3(C_EMB / 64, M_ROWS / 128), 256, 0, stream>>>(
      Xb, Wout, out_b, M_ROWS, C_EMB, C_EMB, x, x2);

  // LN2
  ln_kernel<<<M_ROWS, 256, 0, stream>>>(x2, ln2_g, ln2_b, Xb);

  // FC1 + GELU (128x128, grid 1024 -> 2 blocks/CU) -> H1 (bf16)
  gemmW128<2><<<dim3(HIDDEN_DIM / 128, M_ROWS / 128), 256, 0, stream>>>(
      Xb, W1, fc1_b, M_ROWS, HIDDEN_DIM, C_EMB,
      nullptr, nullptr, H1);

  // FC2 (128x64, grid 512, K=4096): out = H1@W2 + bias + x2
  gemmW<<<dim3(C_EMB / 64, M_ROWS / 128), 256, 0, stream>>>(
      H1, W2, fc2_b, M_ROWS, C_EMB, HIDDEN_DIM, x2, out);
}

// Round 15
// 232.145 us; speedup vs baseline: 1.1044x; 1.1044x over previous
//
#include <hip/hip_runtime.h>
#include <hip/hip_bf16.h>
#include <math.h>

typedef float f32x4 __attribute__((ext_vector_type(4)));
typedef __bf16 bf16x8 __attribute__((ext_vector_type(8)));
typedef __hip_bfloat16 bf16;

constexpr int T_SEQ = 2048;
constexpr int C_EMB = 1024;
constexpr int N_HEAD = 16;
constexpr int D_HEAD = 64;
constexpr int BATCH = 2;
constexpr int M_ROWS = BATCH * T_SEQ;   // 4096
constexpr int HIDDEN_DIM = 4096;

static __device__ __forceinline__ f32x4 zero4() {
  f32x4 z; z[0] = 0.f; z[1] = 0.f; z[2] = 0.f; z[3] = 0.f; return z;
}

static __device__ __forceinline__ void gl_lds16(const bf16* g, bf16* l) {
  __builtin_amdgcn_global_load_lds(
      (const __attribute__((address_space(1))) unsigned int*)g,
      (__attribute__((address_space(3))) unsigned int*)l, 16, 0, 0);
}

#define BAR() asm volatile("s_barrier" ::: "memory")

// ---------------- merged preproc: weight cast+transpose (4 weights) + LN1 ----------------
__global__ __launch_bounds__(256) void preproc(
    const float* __restrict__ qkv_w, bf16* __restrict__ Wqkv,
    const float* __restrict__ out_w, bf16* __restrict__ Wout,
    const float* __restrict__ fc1_w, bf16* __restrict__ W1,
    const float* __restrict__ fc2_w, bf16* __restrict__ W2,
    const float* __restrict__ x, const float* __restrict__ gamma,
    const float* __restrict__ beta, bf16* __restrict__ xb) {
  __shared__ float smem[32 * 33];
  int id = blockIdx.x;
  int t = threadIdx.x;
  if (id >= 12288) {
    int row = id - 12288;
    const float* xr = x + (size_t)row * C_EMB;
    float4 v = *(const float4*)&xr[t * 4];
    float s = v.x + v.y + v.z + v.w;
    float ss = v.x * v.x + v.y * v.y + v.z * v.z + v.w * v.w;
#pragma unroll
    for (int off = 32; off > 0; off >>= 1) {
      s += __shfl_down(s, off, 64);
      ss += __shfl_down(ss, off, 64);
    }
    int w = t >> 6;
    if ((t & 63) == 0) { smem[w] = s; smem[4 + w] = ss; }
    __syncthreads();
    s = smem[0] + smem[1] + smem[2] + smem[3];
    ss = smem[4] + smem[5] + smem[6] + smem[7];
    float mu = s * (1.0f / C_EMB);
    float var = ss * (1.0f / C_EMB) - mu * mu;
    float rstd = rsqrtf(var + 1e-5f);
    float4 g4 = *(const float4*)&gamma[t * 4];
    float4 b4 = *(const float4*)&beta[t * 4];
    bf16* orow = xb + (size_t)row * C_EMB + t * 4;
    orow[0] = __float2bfloat16((v.x - mu) * rstd * g4.x + b4.x);
    orow[1] = __float2bfloat16((v.y - mu) * rstd * g4.y + b4.y);
    orow[2] = __float2bfloat16((v.z - mu) * rstd * g4.z + b4.z);
    orow[3] = __float2bfloat16((v.w - mu) * rstd * g4.w + b4.w);
    return;
  }
  const float* src; bf16* dst; int K, N, tt;
  if (id < 3072)      { src = qkv_w; dst = Wqkv; K = 1024; N = 3072; tt = id; }
  else if (id < 4096) { src = out_w; dst = Wout; K = 1024; N = 1024; tt = id - 3072; }
  else if (id < 8192) { src = fc1_w; dst = W1;   K = 1024; N = 4096; tt = id - 4096; }
  else                { src = fc2_w; dst = W2;   K = 4096; N = 1024; tt = id - 8192; }
  int ntx = N >> 5;
  int n0 = (tt % ntx) * 32, k0 = (tt / ntx) * 32;
  float (*tile)[33] = (float(*)[33])smem;
  int tx = t & 31, ty = t >> 5;
#pragma unroll
  for (int i = 0; i < 4; ++i)
    tile[ty + 8 * i][tx] = src[(size_t)(k0 + ty + 8 * i) * N + n0 + tx];
  __syncthreads();
#pragma unroll
  for (int i = 0; i < 4; ++i)
    dst[(size_t)(n0 + ty + 8 * i) * K + k0 + tx] = __float2bfloat16(tile[tx][ty + 8 * i]);
}

// ---------------- LayerNorm: fp32 in -> bf16 out ----------------
__global__ __launch_bounds__(256) void ln_kernel(const float* __restrict__ x,
                                                 const float* __restrict__ gamma,
                                                 const float* __restrict__ beta,
                                                 bf16* __restrict__ out) {
  int row = blockIdx.x;
  const float* xr = x + (size_t)row * C_EMB;
  int t = threadIdx.x;
  float4 v = *(const float4*)&xr[t * 4];
  float s = v.x + v.y + v.z + v.w;
  float ss = v.x * v.x + v.y * v.y + v.z * v.z + v.w * v.w;
#pragma unroll
  for (int off = 32; off > 0; off >>= 1) {
    s += __shfl_down(s, off, 64);
    ss += __shfl_down(ss, off, 64);
  }
  __shared__ float sbuf[8];
  int w = t >> 6;
  if ((t & 63) == 0) { sbuf[w] = s; sbuf[4 + w] = ss; }
  __syncthreads();
  s = sbuf[0] + sbuf[1] + sbuf[2] + sbuf[3];
  ss = sbuf[4] + sbuf[5] + sbuf[6] + sbuf[7];
  float mu = s * (1.0f / C_EMB);
  float var = ss * (1.0f / C_EMB) - mu * mu;
  float rstd = rsqrtf(var + 1e-5f);
  float4 g4 = *(const float4*)&gamma[t * 4];
  float4 b4 = *(const float4*)&beta[t * 4];
  bf16* orow = out + (size_t)row * C_EMB + t * 4;
  orow[0] = __float2bfloat16((v.x - mu) * rstd * g4.x + b4.x);
  orow[1] = __float2bfloat16((v.y - mu) * rstd * g4.y + b4.y);
  orow[2] = __float2bfloat16((v.z - mu) * rstd * g4.z + b4.z);
  orow[3] = __float2bfloat16((v.w - mu) * rstd * g4.w + b4.w);
}

// ---------------- V transpose: [BH][T][D] -> [BH][D][T] (bf16) ----------------
__global__ __launch_bounds__(256) void transpose_v(const bf16* __restrict__ V,
                                                   bf16* __restrict__ Vt) {
  int tt = blockIdx.x, bh = blockIdx.y;
  __shared__ bf16 tile[64][72];
  const bf16* src = V + ((size_t)bh * T_SEQ + tt * 64) * 64;
  int t = threadIdx.x;
  for (int idx = t; idx < 512; idx += 256) {
    int r = idx >> 3, c = (idx & 7) * 8;
    *(int4*)&tile[r][c] = *(const int4*)&src[r * 64 + c];
  }
  __syncthreads();
  bf16* dst = Vt + ((size_t)bh * 64) * T_SEQ + tt * 64;
  for (int idx = t; idx < 512; idx += 256) {
    int d = idx >> 3, c = (idx & 7) * 8;
    union { bf16 h[8]; int4 v; } u;
#pragma unroll
    for (int j = 0; j < 8; ++j) u.h[j] = tile[c + j][d];
    *(int4*)&dst[(size_t)d * T_SEQ + c] = u.v;
  }
}

// ---------------- GEMM 256x256, BK=64, 8 waves, 8-phase (r10-proven) ----------------
// EPI 0: scatter Q(,*0.125)/K/V -> [B,H,T,D] (coalesced); EPI 2: gelu -> bf16.
template <int EPI>
__global__ __launch_bounds__(512) void gemm8p(
    const bf16* __restrict__ A, const bf16* __restrict__ Bt,
    const float* __restrict__ bias, int M, int N, int K,
    bf16* __restrict__ out_b16,
    bf16* __restrict__ q_out, bf16* __restrict__ k_out, bf16* __restrict__ v_out) {
  constexpr int NFR = 4;                  // BN=256
  __shared__ bf16 Asl[2][2][128 * 64];
  __shared__ bf16 Bsl[2][2][128 * 64];

  int gx = gridDim.x, nwg = gx * gridDim.y;
  int flat = blockIdx.y * gx + blockIdx.x;
  int swz = (flat & 7) * (nwg >> 3) + (flat >> 3);
  int bx = swz % gx, by = swz / gx;

  int m0 = by * 256, n0 = bx * 256;
  int t = threadIdx.x;
  int wv = t >> 6, lane = t & 63, g = lane >> 4, r16 = lane & 15;
  int wm = wv >> 2, wn = wv & 3;          // 2M x 4N wave grid

  f32x4 acc[8][NFR];
#pragma unroll
  for (int i = 0; i < 8; ++i)
#pragma unroll
    for (int j = 0; j < NFR; ++j) acc[i][j] = zero4();

  int lrow8 = lane >> 3;
  int srcg = (lane & 7) ^ lrow8;
  int NT = K / 64;

  auto stageA = [&](int tile, int h) {
    int par = tile & 1;
    const bf16* base = A + (size_t)(m0 + h * 128) * K + tile * 64;
#pragma unroll
    for (int j = 0; j < 2; ++j) {
      const bf16* src = base + (size_t)((wv * 2 + j) * 8 + lrow8) * K + srcg * 8;
      gl_lds16(src, &Asl[par][h][((wv * 2 + j) * 8) * 64]);
    }
  };
  auto stageB = [&](int tile, int h) {
    int par = tile & 1;
    const bf16* base = Bt + (size_t)(n0 + h * 128) * K + tile * 64;
#pragma unroll
    for (int j = 0; j < 2; ++j) {
      const bf16* src = base + (size_t)((wv * 2 + j) * 8 + lrow8) * K + srcg * 8;
      gl_lds16(src, &Bsl[par][h][((wv * 2 + j) * 8) * 64]);
    }
  };

  int xk[2];
#pragma unroll
  for (int kk = 0; kk < 2; ++kk) xk[kk] = (((kk * 4 + g) ^ (r16 & 7)) << 3);
  int bhalf = wn >> 1;
  int blrow0 = (wn & 1) * 64;

  stageA(0, 0); stageA(0, 1); stageB(0, 0); stageB(0, 1);
  if (NT > 1) {
    stageB(1, 0); stageB(1, 1);
    asm volatile("s_waitcnt vmcnt(4)" ::: "memory");
  } else {
    asm volatile("s_waitcnt vmcnt(0)" ::: "memory");
  }
  BAR();

  bf16x8 bfr[NFR][2];

  for (int u = 0; u < NT; ++u) {
    int par = u & 1;
    const bf16* Ab = &Asl[par][wm][0];
    const bf16* Bb = &Bsl[par][bhalf][0];
#pragma unroll
    for (int q = 0; q < 4; ++q) {
      if (q == 0) {
#pragma unroll
        for (int ni = 0; ni < NFR; ++ni)
#pragma unroll
          for (int kk = 0; kk < 2; ++kk)
            bfr[ni][kk] = *(const bf16x8*)&Bb[(blrow0 + ni * 16 + r16) * 64 + xk[kk]];
      }
      bf16x8 af[2][2];
#pragma unroll
      for (int d = 0; d < 2; ++d)
#pragma unroll
        for (int kk = 0; kk < 2; ++kk)
          af[d][kk] = *(const bf16x8*)&Ab[((2 * q + d) * 16 + r16) * 64 + xk[kk]];
      if (q == 0) { if (u + 1 < NT) stageA(u + 1, 0); }
      else if (q == 1) { if (u + 1 < NT) stageA(u + 1, 1); }
      else if (q == 2) { if (u + 2 < NT) stageB(u + 2, 0); }
      else { if (u + 2 < NT) stageB(u + 2, 1); }
      BAR();
      asm volatile("s_waitcnt lgkmcnt(0)" ::: "memory");
      __builtin_amdgcn_sched_barrier(0);
      __builtin_amdgcn_s_setprio(1);
#pragma unroll
      for (int d = 0; d < 2; ++d)
#pragma unroll
        for (int ni = 0; ni < NFR; ++ni) {
          acc[2 * q + d][ni] = __builtin_amdgcn_mfma_f32_16x16x32_bf16(af[d][0], bfr[ni][0], acc[2 * q + d][ni], 0, 0, 0);
          acc[2 * q + d][ni] = __builtin_amdgcn_mfma_f32_16x16x32_bf16(af[d][1], bfr[ni][1], acc[2 * q + d][ni], 0, 0, 0);
        }
      __builtin_amdgcn_s_setprio(0);
      if (q == 3) {
        if (u + 2 < NT)
          asm volatile("s_waitcnt vmcnt(4)" ::: "memory");
        else
          asm volatile("s_waitcnt vmcnt(0)" ::: "memory");
      }
      BAR();
    }
  }

#pragma unroll
  for (int mi = 0; mi < 8; ++mi) {
#pragma unroll
    for (int ni = 0; ni < NFR; ++ni) {
      int col = n0 + wn * 64 + ni * 16 + r16;
      float bv = bias[col];
#pragma unroll
      for (int reg = 0; reg < 4; ++reg) {
        int row = m0 + wm * 128 + mi * 16 + g * 4 + reg;
        float v = acc[mi][ni][reg] + bv;
        if constexpr (EPI == 0) {
          int part = col >> 10, cc = col & 1023;
          int hh = cc >> 6, dd = cc & 63;
          int bb = row >> 11, tt2 = row & 2047;
          size_t idx = (((size_t)bb * N_HEAD + hh) * T_SEQ + tt2) * D_HEAD + dd;
          if (part == 0) q_out[idx] = __float2bfloat16(v * 0.125f);
          else if (part == 1) k_out[idx] = __float2bfloat16(v);
          else v_out[idx] = __float2bfloat16(v);
        } else {
          float ge = 0.5f * v * (1.0f + erff(v * 0.70710678118f));
          out_b16[(size_t)row * N + col] = __float2bfloat16(ge);
        }
      }
    }
  }
}

// ---------------- GEMM 128x64, BK=64, 4 waves, 48KB LDS (r12-proven) ----
// out = acc + bias + res (fp32).
__global__ __launch_bounds__(256) void gemmW(
    const bf16* __restrict__ A, const bf16* __restrict__ Bt,
    const float* __restrict__ bias, int M, int N, int K,
    const float* __restrict__ res, float* __restrict__ out_f32) {
  __shared__ bf16 Abuf[2][128 * 64];
  __shared__ bf16 Bbuf[2][64 * 64];

  int gx = gridDim.x, nwg = gx * gridDim.y;
  int flat = blockIdx.y * gx + blockIdx.x;
  int swz = (flat & 7) * (nwg >> 3) + (flat >> 3);
  int bx = swz % gx, by = swz / gx;

  int m0 = by * 128, n0 = bx * 64;
  int t = threadIdx.x;
  int wv = t >> 6, lane = t & 63, g = lane >> 4, r16 = lane & 15;
  int wm = wv >> 1, wn = wv & 1;

  f32x4 acc[4][2];
#pragma unroll
  for (int i = 0; i < 4; ++i)
#pragma unroll
    for (int j = 0; j < 2; ++j) acc[i][j] = zero4();

  int lrow8 = lane >> 3;
  int srcg = (lane & 7) ^ lrow8;
  int NT = K / 64;

  const bf16* gAp[4];
  const bf16* gBp[2];
#pragma unroll
  for (int i = 0; i < 4; ++i)
    gAp[i] = A + (size_t)(m0 + (wv * 4 + i) * 8 + lrow8) * K + srcg * 8;
#pragma unroll
  for (int i = 0; i < 2; ++i)
    gBp[i] = Bt + (size_t)(n0 + (wv * 2 + i) * 8 + lrow8) * K + srcg * 8;

  int aoff[4], boff[2], xk[2];
#pragma unroll
  for (int mi = 0; mi < 4; ++mi) aoff[mi] = (wm * 64 + mi * 16 + r16) * 64;
#pragma unroll
  for (int ni = 0; ni < 2; ++ni) boff[ni] = (wn * 32 + ni * 16 + r16) * 64;
#pragma unroll
  for (int kk = 0; kk < 2; ++kk) xk[kk] = (((kk * 4 + g) ^ (r16 & 7)) << 3);

  auto stage = [&](int buf) {
#pragma unroll
    for (int i = 0; i < 4; ++i) {
      gl_lds16(gAp[i], &Abuf[buf][((wv * 4 + i) * 8) * 64]);
      gAp[i] += 64;
    }
#pragma unroll
    for (int i = 0; i < 2; ++i) {
      gl_lds16(gBp[i], &Bbuf[buf][((wv * 2 + i) * 8) * 64]);
      gBp[i] += 64;
    }
  };

  auto compute = [&](int buf) {
    const bf16* Ab = &Abuf[buf][0];
    const bf16* Bb = &Bbuf[buf][0];
    bf16x8 bfr[2][2];
#pragma unroll
    for (int ni = 0; ni < 2; ++ni)
#pragma unroll
      for (int kk = 0; kk < 2; ++kk)
        bfr[ni][kk] = *(const bf16x8*)&Bb[boff[ni] + xk[kk]];
#pragma unroll
    for (int mi = 0; mi < 4; ++mi) {
      bf16x8 a0 = *(const bf16x8*)&Ab[aoff[mi] + xk[0]];
      bf16x8 a1 = *(const bf16x8*)&Ab[aoff[mi] + xk[1]];
#pragma unroll
      for (int ni = 0; ni < 2; ++ni) {
        acc[mi][ni] = __builtin_amdgcn_mfma_f32_16x16x32_bf16(a0, bfr[ni][0], acc[mi][ni], 0, 0, 0);
        acc[mi][ni] = __builtin_amdgcn_mfma_f32_16x16x32_bf16(a1, bfr[ni][1], acc[mi][ni], 0, 0, 0);
      }
    }
  };

  stage(0);
  __syncthreads();
  for (int tt2 = 0; tt2 < NT; ++tt2) {
    int cur = tt2 & 1;
    if (tt2 + 1 < NT) stage(cur ^ 1);
    compute(cur);
    __syncthreads();
  }

#pragma unroll
  for (int mi = 0; mi < 4; ++mi) {
#pragma unroll
    for (int ni = 0; ni < 2; ++ni) {
      int col = n0 + wn * 32 + ni * 16 + r16;
      float bv = bias[col];
#pragma unroll
      for (int reg = 0; reg < 4; ++reg) {
        int row = m0 + wm * 64 + mi * 16 + g * 4 + reg;
        size_t idx = (size_t)row * N + col;
        out_f32[idx] = acc[mi][ni][reg] + bv + res[idx];
      }
    }
  }
}

// ---------------- causal flash attention (round-6 proven version) ----------------
__global__ __launch_bounds__(256) void attn_kernel(const bf16* __restrict__ Q,
                                                   const bf16* __restrict__ Kg,
                                                   const bf16* __restrict__ Vt,
                                                   bf16* __restrict__ O) {
  constexpr int NQ = T_SEQ / 64;   // 32
  int p = blockIdx.x, bh = blockIdx.y;
  int qtA = p, qtB = NQ - 1 - p;
  int b = bh >> 4, h = bh & 15;
  __shared__ bf16 Ks[2][64 * 64];
  __shared__ bf16 Vs[2][64 * 64];
  __shared__ bf16 Ps[4][16 * 64];
  int t = threadIdx.x, w = t >> 6, lane = t & 63, g = lane >> 4, r16 = lane & 15;

  const bf16* QpA = Q + ((size_t)bh * T_SEQ + qtA * 64) * 64;
  const bf16* QpB = Q + ((size_t)bh * T_SEQ + qtB * 64) * 64;
  bf16x8 qfA[2], qfB[2];
#pragma unroll
  for (int kk = 0; kk < 2; ++kk) {
    qfA[kk] = *(const bf16x8*)&QpA[(w * 16 + r16) * 64 + kk * 32 + g * 8];
    qfB[kk] = *(const bf16x8*)&QpB[(w * 16 + r16) * 64 + kk * 32 + g * 8];
  }

  float lsA[4] = {0.f, 0.f, 0.f, 0.f}, lsB[4] = {0.f, 0.f, 0.f, 0.f};
  f32x4 oA[4], oB[4];
#pragma unroll
  for (int i = 0; i < 4; ++i) { oA[i] = zero4(); oB[i] = zero4(); }

  bf16* Psw = Ps[w];

  int sg0 = w * 128 + lane, sg1 = w * 128 + 64 + lane;
  int sr0 = sg0 >> 3, sc0 = (sg0 & 7) ^ (sr0 & 7);
  int sr1 = sg1 >> 3, sc1 = (sg1 & 7) ^ (sr1 & 7);

  auto stage = [&](int kt, int buf) {
    const bf16* Kp = Kg + ((size_t)bh * T_SEQ + kt * 64) * 64;
    const bf16* Vp = Vt + (size_t)bh * 64 * T_SEQ + kt * 64;
    gl_lds16(Kp + sr0 * 64 + sc0 * 8, &Ks[buf][(w * 128) * 8]);
    gl_lds16(Vp + (size_t)sr0 * T_SEQ + sc0 * 8, &Vs[buf][(w * 128) * 8]);
    gl_lds16(Kp + sr1 * 64 + sc1 * 8, &Ks[buf][(w * 128 + 64) * 8]);
    gl_lds16(Vp + (size_t)sr1 * T_SEQ + sc1 * 8, &Vs[buf][(w * 128 + 64) * 8]);
  };

  auto process = [&](const bf16x8* qf, float* ls, f32x4* o_acc, bool diag,
                     const bf16* Ksb, const bf16* Vsb) {
    f32x4 s[4];
#pragma unroll
    for (int ni = 0; ni < 4; ++ni) {
      s[ni] = zero4();
#pragma unroll
      for (int kk = 0; kk < 2; ++kk) {
        bf16x8 kf = *(const bf16x8*)&Ksb[(ni * 16 + r16) * 64 + (((kk * 4 + g) ^ (r16 & 7)) << 3)];
        s[ni] = __builtin_amdgcn_mfma_f32_16x16x32_bf16(qf[kk], kf, s[ni], 0, 0, 0);
      }
    }
    if (diag) {
#pragma unroll
      for (int ni = 0; ni < 4; ++ni) {
        int kl = ni * 16 + r16;
#pragma unroll
        for (int reg = 0; reg < 4; ++reg) {
          int ql = w * 16 + g * 4 + reg;
          if (kl > ql) s[ni][reg] = -1e30f;
        }
      }
    }
#pragma unroll
    for (int ni = 0; ni < 4; ++ni) {
#pragma unroll
      for (int reg = 0; reg < 4; ++reg) {
        float pv = __expf(s[ni][reg]);
        s[ni][reg] = pv;
        ls[reg] += pv;
        int rr = g * 4 + reg;
        Psw[rr * 64 + (((ni * 2 + (r16 >> 3)) ^ (rr & 7)) << 3) + (r16 & 7)] =
            __float2bfloat16(pv);
      }
    }
    bf16x8 pf[2];
#pragma unroll
    for (int kk = 0; kk < 2; ++kk)
      pf[kk] = *(const bf16x8*)&Psw[r16 * 64 + (((kk * 4 + g) ^ (r16 & 7)) << 3)];
#pragma unroll
    for (int nd = 0; nd < 4; ++nd)
#pragma unroll
      for (int kk = 0; kk < 2; ++kk) {
        bf16x8 vf = *(const bf16x8*)&Vsb[(nd * 16 + r16) * 64 + (((kk * 4 + g) ^ (r16 & 7)) << 3)];
        o_acc[nd] = __builtin_amdgcn_mfma_f32_16x16x32_bf16(pf[kk], vf, o_acc[nd], 0, 0, 0);
      }
  };

  stage(0, 0);
  __syncthreads();
  for (int kt = 0; kt <= qtB; ++kt) {
    int cur = kt & 1;
    if (kt + 1 <= qtB) stage(kt + 1, cur ^ 1);
    process(qfB, lsB, oB, kt == qtB, &Ks[cur][0], &Vs[cur][0]);
    if (kt <= qtA) process(qfA, lsA, oA, kt == qtA, &Ks[cur][0], &Vs[cur][0]);
    __syncthreads();
  }

#pragma unroll
  for (int reg = 0; reg < 4; ++reg) {
#pragma unroll
    for (int off = 1; off < 16; off <<= 1) {
      lsA[reg] += __shfl_xor(lsA[reg], off, 64);
      lsB[reg] += __shfl_xor(lsB[reg], off, 64);
    }
  }
#pragma unroll
  for (int reg = 0; reg < 4; ++reg) {
    float invA = 1.0f / lsA[reg];
    float invB = 1.0f / lsB[reg];
    int rowA = b * T_SEQ + qtA * 64 + w * 16 + g * 4 + reg;
    int rowB = b * T_SEQ + qtB * 64 + w * 16 + g * 4 + reg;
#pragma unroll
    for (int nd = 0; nd < 4; ++nd) {
      int col = h * 64 + nd * 16 + r16;
      O[(size_t)rowA * C_EMB + col] = __float2bfloat16(oA[nd][reg] * invA);
      O[(size_t)rowB * C_EMB + col] = __float2bfloat16(oB[nd][reg] * invB);
    }
  }
}

extern "C" void kernel_launch(void* const* d_in, const int* in_sizes, int n_in,
                              void* d_out, int out_size, void* d_ws, size_t ws_size,
                              hipStream_t stream) {
  (void)in_sizes; (void)n_in; (void)out_size; (void)ws_size;
  const float* x     = (const float*)d_in[0];
  const float* ln1_g = (const float*)d_in[1];
  const float* ln1_b = (const float*)d_in[2];
  const float* qkv_w = (const float*)d_in[3];
  const float* qkv_b = (const float*)d_in[4];
  const float* out_w = (const float*)d_in[5];
  const float* out_b = (const float*)d_in[6];
  const float* ln2_g = (const float*)d_in[7];
  const float* ln2_b = (const float*)d_in[8];
  const float* fc1_w = (const float*)d_in[9];
  const float* fc1_b = (const float*)d_in[10];
  const float* fc2_w = (const float*)d_in[11];
  const float* fc2_b = (const float*)d_in[12];
  float* out = (float*)d_out;

  char* ws = (char*)d_ws;
  size_t off = 0;
  auto alloc = [&](size_t bytes) {
    void* p = ws + off;
    off += (bytes + 255) & ~(size_t)255;
    return p;
  };
  bf16* Wqkv = (bf16*)alloc((size_t)3 * C_EMB * C_EMB * 2);          // 6MB
  bf16* Wout = (bf16*)alloc((size_t)C_EMB * C_EMB * 2);              // 2MB
  bf16* W1   = (bf16*)alloc((size_t)HIDDEN_DIM * C_EMB * 2);         // 8MB
  bf16* W2   = (bf16*)alloc((size_t)C_EMB * HIDDEN_DIM * 2);         // 8MB
  float* x2  = (float*)alloc((size_t)M_ROWS * C_EMB * 4);            // fp32 residual stream
  bf16* Xb   = (bf16*)alloc((size_t)M_ROWS * C_EMB * 2);             // X1 / O / X2n
  bf16* Qb   = (bf16*)alloc((size_t)M_ROWS * C_EMB * 2 * 4);         // Q,K,V,Vt ; later H1
  bf16* Kb   = Qb + (size_t)M_ROWS * C_EMB;
  bf16* Vb   = Kb + (size_t)M_ROWS * C_EMB;
  bf16* Vtb  = Vb + (size_t)M_ROWS * C_EMB;
  bf16* H1   = Qb;                                                    // reuse (32MB)

  // merged weight cast + LN1 (1 launch)
  preproc<<<16384, 256, 0, stream>>>(qkv_w, Wqkv, out_w, Wout, fc1_w, W1, fc2_w, W2,
                                     x, ln1_g, ln1_b, Xb);

  // QKV projection (8-phase 256x256), scatter to per-head layout (Q pre-scaled by 1/8)
  gemm8p<0><<<dim3(3 * C_EMB / 256, M_ROWS / 256), 512, 0, stream>>>(
      Xb, Wqkv, qkv_b, M_ROWS, 3 * C_EMB, C_EMB,
      nullptr, Qb, Kb, Vb);

  // V -> Vt [BH][D][T]
  transpose_v<<<dim3(T_SEQ / 64, BATCH * N_HEAD), 256, 0, stream>>>(Vb, Vtb);

  // attention -> O (Xb, [B,T,C])
  attn_kernel<<<dim3(T_SEQ / 128, BATCH * N_HEAD), 256, 0, stream>>>(Qb, Kb, Vtb, Xb);

  // out-proj (128x64, grid 512): x2 = attnout@Wout + bias + x
  gemmW<<<dim3(C_EMB / 64, M_ROWS / 128), 256, 0, stream>>>(
      Xb, Wout, out_b, M_ROWS, C_EMB, C_EMB, x, x2);

  // LN2
  ln_kernel<<<M_ROWS, 256, 0, stream>>>(x2, ln2_g, ln2_b, Xb);

  // FC1 + GELU (8-phase 256x256) -> H1 (bf16)
  gemm8p<2><<<dim3(HIDDEN_DIM / 256, M_ROWS / 256), 512, 0, stream>>>(
      Xb, W1, fc1_b, M_ROWS, HIDDEN_DIM, C_EMB,
      H1, nullptr, nullptr, nullptr);

  // FC2 (128x64, grid 512, K=4096): out = H1@W2 + bias + x2
  gemmW<<<dim3(C_EMB / 64, M_ROWS / 128), 256, 0, stream>>>(
      H1, W2, fc2_b, M_ROWS, C_EMB, HIDDEN_DIM, x2, out);
}